// Round 2
// baseline (72.314 us; speedup 1.0000x reference)
//
#include <hip/hip_runtime.h>

#define BATCH 256
#define KDIM 1024
#define NFEAT 64
#define KD 16
#define NCOL (NFEAT * KD)  // 1024

// ---------------------------------------------------------------------------
// Kernel 1: M = x @ T  (256x1024 @ 1024x1024 fp32), K-split with atomic reduce.
// grid 512 = (ksplit 8) x (coltile 16) x (rowtile 4); block 256 threads.
// Tile: 64 rows x 64 cols, K-range 128 per block, staged in K-chunks of 32.
// Thread tile 4x4 (16 acc). xs is transposed [k][row] so both fragment reads
// are single float4 ds_reads (x read is 16-lane broadcast, T read 2-way).
// Global->reg prefetch of chunk c+1 issued before computing chunk c.
// ---------------------------------------------------------------------------
__global__ __launch_bounds__(256, 2) void md_gemm(const float* __restrict__ x,
                                                  const float* __restrict__ T,
                                                  float* __restrict__ M) {
  __shared__ float xs[32 * 64];  // [k][row], 8 KB
  __shared__ float ts[32 * 64];  // [k][col], 8 KB
  const int tid = threadIdx.x;
  const int b = blockIdx.x;
  const int rt = b & 3;
  const int ct = (b >> 2) & 15;
  const int ks = b >> 6;
  const int r0 = rt * 64, c0 = ct * 64, k0 = ks * 128;
  const int ty = tid >> 4, tx = tid & 15;

  const float4* x4 = (const float4*)x;
  const float4* T4 = (const float4*)T;

  // staging index decomposition (2 float4 per thread per operand per chunk)
  // x: flat = i*256+tid -> row = flat&63 (lane-consecutive), c4g = flat>>6
  // T: flat = i*256+tid -> kr = flat>>4, c4 = flat&15 (lane-consecutive)
  float4 gx[2], gt[2];
  int kc = k0;
#pragma unroll
  for (int i = 0; i < 2; ++i) {
    int flat = i * 256 + tid;
    int row = flat & 63, c4g = flat >> 6;
    gx[i] = x4[(size_t)(r0 + row) * 256 + (kc >> 2) + c4g];
    int kr = flat >> 4, c4 = flat & 15;
    gt[i] = T4[(size_t)(kc + kr) * 256 + (c0 >> 2) + c4];
  }

  float acc[4][4] = {};

  for (int c = 0; c < 4; ++c) {
    __syncthreads();
#pragma unroll
    for (int i = 0; i < 2; ++i) {
      int flat = i * 256 + tid;
      int row = flat & 63, c4g = flat >> 6;
      xs[(c4g * 4 + 0) * 64 + row] = gx[i].x;  // b32 scatter: banks = row%32, 2-way
      xs[(c4g * 4 + 1) * 64 + row] = gx[i].y;
      xs[(c4g * 4 + 2) * 64 + row] = gx[i].z;
      xs[(c4g * 4 + 3) * 64 + row] = gx[i].w;
      int kr = flat >> 4, c4 = flat & 15;
      *(float4*)&ts[kr * 64 + c4 * 4] = gt[i];
    }
    __syncthreads();
    if (c < 3) {  // prefetch next chunk; latency hides under compute below
      int kn = kc + 32;
#pragma unroll
      for (int i = 0; i < 2; ++i) {
        int flat = i * 256 + tid;
        int row = flat & 63, c4g = flat >> 6;
        gx[i] = x4[(size_t)(r0 + row) * 256 + (kn >> 2) + c4g];
        int kr = flat >> 4, c4 = flat & 15;
        gt[i] = T4[(size_t)(kn + kr) * 256 + (c0 >> 2) + c4];
      }
      kc = kn;
    }
#pragma unroll
    for (int k = 0; k < 32; ++k) {
      float4 xv = *(const float4*)&xs[k * 64 + ty * 4];  // broadcast, free
      float4 tv = *(const float4*)&ts[k * 64 + tx * 4];  // 2-way, free
      float xr[4] = {xv.x, xv.y, xv.z, xv.w};
      float tc[4] = {tv.x, tv.y, tv.z, tv.w};
#pragma unroll
      for (int i = 0; i < 4; ++i)
#pragma unroll
        for (int j = 0; j < 4; ++j) acc[i][j] = fmaf(xr[i], tc[j], acc[i][j]);
    }
  }

#pragma unroll
  for (int i = 0; i < 4; ++i)
#pragma unroll
    for (int j = 0; j < 4; ++j)
      atomicAdd(&M[(size_t)(r0 + ty * 4 + i) * NCOL + c0 + tx * 4 + j], acc[i][j]);
}

// ---------------------------------------------------------------------------
// Kernel 2: out[i,f] = sum_j exp(-sum_k |M[i,f,k]-M[j,f,k]|) - 1
// grid 1024: f = b>>4, j-tile jt = b&15 (16 j's). block 256 threads = i.
// Self term cancelled by acc = -1 in the tile containing j == i.
// ---------------------------------------------------------------------------
__global__ __launch_bounds__(256) void md_pairwise(const float* __restrict__ M,
                                                   float* __restrict__ out) {
  __shared__ float ms[16 * KD];  // 1 KB
  const int tid = threadIdx.x;
  const int f = blockIdx.x >> 4;
  const int jt = blockIdx.x & 15;
  const int j0 = jt * 16;

  if (tid < 64) {
    int j = tid >> 2, kc = tid & 3;
    *(float4*)&ms[j * KD + kc * 4] =
        *(const float4*)&M[(size_t)(j0 + j) * NCOL + f * KD + kc * 4];
  }

  float m[KD];
#pragma unroll
  for (int kc = 0; kc < 4; ++kc) {
    float4 v = *(const float4*)&M[(size_t)tid * NCOL + f * KD + kc * 4];
    m[kc * 4 + 0] = v.x;
    m[kc * 4 + 1] = v.y;
    m[kc * 4 + 2] = v.z;
    m[kc * 4 + 3] = v.w;
  }
  __syncthreads();

  float acc = ((tid >> 4) == jt) ? -1.0f : 0.0f;
#pragma unroll
  for (int j = 0; j < 16; ++j) {
    float l1 = 0.f;
#pragma unroll
    for (int k = 0; k < KD; ++k) l1 += fabsf(m[k] - ms[j * KD + k]);
    acc += __expf(-l1);
  }
  atomicAdd(&out[(size_t)tid * NFEAT + f], acc);
}

extern "C" void kernel_launch(void* const* d_in, const int* in_sizes, int n_in,
                              void* d_out, int out_size, void* d_ws, size_t ws_size,
                              hipStream_t stream) {
  const float* x = (const float*)d_in[0];
  const float* T = (const float*)d_in[1];
  float* out = (float*)d_out;
  float* M = (float*)d_ws;  // 1 MB scratch

  hipMemsetAsync(M, 0, (size_t)BATCH * NCOL * sizeof(float), stream);
  hipMemsetAsync(out, 0, (size_t)BATCH * NFEAT * sizeof(float), stream);
  md_gemm<<<512, 256, 0, stream>>>(x, T, M);
  md_pairwise<<<1024, 256, 0, stream>>>(M, out);
}

// Round 3
// 49.722 us; speedup vs baseline: 1.4544x; 1.4544x over previous
//
#include <hip/hip_runtime.h>

#define BATCH 256
#define KDIM 1024
#define NFEAT 64
#define KD 16
#define NCOL (NFEAT * KD)  // 1024

typedef __attribute__((ext_vector_type(8))) short bf16x8;   // 8 bf16 (4 VGPR)
typedef __attribute__((ext_vector_type(4))) float f32x4;    // MFMA C/D
typedef __attribute__((ext_vector_type(4))) unsigned int u32x4;

__device__ __forceinline__ unsigned int bf16_hi(float f) {
  return __builtin_bit_cast(unsigned int, f) >> 16;  // truncation: residual goes to lo
}

// ---------------------------------------------------------------------------
// Kernel 1: prep. Blocks 0..255: transpose+convert T (1024x1024 f32, k-major)
// into Th/Tl [col][k] bf16 via a 64x64 LDS tile. Blocks 256..263: convert x
// row-major into xh/xl bf16 (k already contiguous).
// Split: xh = bf16_trunc(x), xl = bf16_trunc(x - xh)  (rel err ~2^-16).
// ---------------------------------------------------------------------------
__global__ __launch_bounds__(256) void md_prep(const float* __restrict__ x,
                                               const float* __restrict__ T,
                                               ushort* __restrict__ Th,
                                               ushort* __restrict__ Tl,
                                               ushort* __restrict__ xh,
                                               ushort* __restrict__ xl) {
  const int t = threadIdx.x;
  const int b = blockIdx.x;
  if (b < 256) {
    __shared__ float lds[64][65];  // +1 pad: transpose-read conflict-free
    const int k0 = (b >> 4) * 64, c0 = (b & 15) * 64;
    const float4* T4 = (const float4*)T;
#pragma unroll
    for (int rr = 0; rr < 4; ++rr) {
      int row = rr * 16 + (t >> 4);
      float4 v = T4[(size_t)(k0 + row) * 256 + (c0 >> 2) + (t & 15)];
      lds[row][(t & 15) * 4 + 0] = v.x;
      lds[row][(t & 15) * 4 + 1] = v.y;
      lds[row][(t & 15) * 4 + 2] = v.z;
      lds[row][(t & 15) * 4 + 3] = v.w;
    }
    __syncthreads();
    const int col = t >> 2, kc = (t & 3) * 16;
    unsigned int wh[8], wl[8];
#pragma unroll
    for (int kk = 0; kk < 16; ++kk) {
      float f = lds[kc + kk][col];
      unsigned int h = bf16_hi(f);
      float r = f - __builtin_bit_cast(float, h << 16);
      unsigned int lo = bf16_hi(r);
      if (kk & 1) { wh[kk >> 1] |= h << 16; wl[kk >> 1] |= lo << 16; }
      else        { wh[kk >> 1] = h;        wl[kk >> 1] = lo; }
    }
    size_t off = ((size_t)(c0 + col) * KDIM + k0 + kc) >> 1;  // u32 index
    u32x4* ph = (u32x4*)((unsigned int*)Th + off);
    u32x4* pl = (u32x4*)((unsigned int*)Tl + off);
    ph[0] = u32x4{wh[0], wh[1], wh[2], wh[3]};
    ph[1] = u32x4{wh[4], wh[5], wh[6], wh[7]};
    pl[0] = u32x4{wl[0], wl[1], wl[2], wl[3]};
    pl[1] = u32x4{wl[4], wl[5], wl[6], wl[7]};
  } else {
    const float4* x4 = (const float4*)x;
    uint2* xh2 = (uint2*)xh;
    uint2* xl2 = (uint2*)xl;
    int base = (b - 256) * 256 + t;
#pragma unroll
    for (int i = 0; i < 32; ++i) {
      int idx = base + i * 2048;  // 65536 float4 total
      float4 v = x4[idx];
      unsigned int h0 = bf16_hi(v.x), h1 = bf16_hi(v.y), h2 = bf16_hi(v.z), h3 = bf16_hi(v.w);
      float r0 = v.x - __builtin_bit_cast(float, h0 << 16);
      float r1 = v.y - __builtin_bit_cast(float, h1 << 16);
      float r2 = v.z - __builtin_bit_cast(float, h2 << 16);
      float r3 = v.w - __builtin_bit_cast(float, h3 << 16);
      xh2[idx] = make_uint2(h0 | (h1 << 16), h2 | (h3 << 16));
      xl2[idx] = make_uint2(bf16_hi(r0) | (bf16_hi(r1) << 16),
                            bf16_hi(r2) | (bf16_hi(r3) << 16));
    }
  }
}

// ---------------------------------------------------------------------------
// Kernel 2: MFMA GEMM. M = xh*Th + xh*Tl + xl*Th (3-product split-bf16).
// Wave = 32x32 out tile, K=128 slice. 2048 waves (512 blocks): tc=W&31,
// tr=(W>>5)&7, ks=W>>8. Frags read straight from global (16B contiguous in k,
// both operands — Tt is pre-transposed). Partials to Mp[ks] (no atomics).
// Block's 4 waves share tr,ks (identical A addresses -> L1 broadcast).
// ---------------------------------------------------------------------------
__global__ __launch_bounds__(256, 2) void md_mfma(const ushort* __restrict__ xh,
                                                  const ushort* __restrict__ xl,
                                                  const ushort* __restrict__ Th,
                                                  const ushort* __restrict__ Tl,
                                                  float* __restrict__ Mp) {
  const int tid = threadIdx.x;
  const int l = tid & 63;
  const int W = blockIdx.x * 4 + (tid >> 6);
  const int tc = W & 31, tr = (W >> 5) & 7, ks = W >> 8;
  const int r0 = tr * 32, c0 = tc * 32, k0 = ks * 128;
  const int l16 = l & 15, g = l >> 4;

  const ushort* pah = xh + (size_t)(r0 + l16) * KDIM + k0 + 8 * g;
  const ushort* pal = xl + (size_t)(r0 + l16) * KDIM + k0 + 8 * g;
  const ushort* pbh = Th + (size_t)(c0 + l16) * KDIM + k0 + 8 * g;
  const ushort* pbl = Tl + (size_t)(c0 + l16) * KDIM + k0 + 8 * g;

  f32x4 c00 = {0.f, 0.f, 0.f, 0.f}, c01 = c00, c10 = c00, c11 = c00;

#pragma unroll
  for (int s = 0; s < 4; ++s) {
    const int o = s * 32;
    bf16x8 ah0 = *(const bf16x8*)(pah + o);
    bf16x8 ah1 = *(const bf16x8*)(pah + o + 16 * KDIM);
    bf16x8 al0 = *(const bf16x8*)(pal + o);
    bf16x8 al1 = *(const bf16x8*)(pal + o + 16 * KDIM);
    bf16x8 bh0 = *(const bf16x8*)(pbh + o);
    bf16x8 bh1 = *(const bf16x8*)(pbh + o + 16 * KDIM);
    bf16x8 bl0 = *(const bf16x8*)(pbl + o);
    bf16x8 bl1 = *(const bf16x8*)(pbl + o + 16 * KDIM);

    c00 = __builtin_amdgcn_mfma_f32_16x16x32_bf16(ah0, bh0, c00, 0, 0, 0);
    c01 = __builtin_amdgcn_mfma_f32_16x16x32_bf16(ah0, bh1, c01, 0, 0, 0);
    c10 = __builtin_amdgcn_mfma_f32_16x16x32_bf16(ah1, bh0, c10, 0, 0, 0);
    c11 = __builtin_amdgcn_mfma_f32_16x16x32_bf16(ah1, bh1, c11, 0, 0, 0);
    c00 = __builtin_amdgcn_mfma_f32_16x16x32_bf16(ah0, bl0, c00, 0, 0, 0);
    c01 = __builtin_amdgcn_mfma_f32_16x16x32_bf16(ah0, bl1, c01, 0, 0, 0);
    c10 = __builtin_amdgcn_mfma_f32_16x16x32_bf16(ah1, bl0, c10, 0, 0, 0);
    c11 = __builtin_amdgcn_mfma_f32_16x16x32_bf16(ah1, bl1, c11, 0, 0, 0);
    c00 = __builtin_amdgcn_mfma_f32_16x16x32_bf16(al0, bh0, c00, 0, 0, 0);
    c01 = __builtin_amdgcn_mfma_f32_16x16x32_bf16(al0, bh1, c01, 0, 0, 0);
    c10 = __builtin_amdgcn_mfma_f32_16x16x32_bf16(al1, bh0, c10, 0, 0, 0);
    c11 = __builtin_amdgcn_mfma_f32_16x16x32_bf16(al1, bh1, c11, 0, 0, 0);
  }

  float* mp = Mp + (size_t)ks * (BATCH * NCOL);
#pragma unroll
  for (int reg = 0; reg < 4; ++reg) {
    int ro = g * 4 + reg;  // C/D: col = lane&15, row = (lane>>4)*4 + reg
    mp[(size_t)(r0 + ro) * NCOL + c0 + l16]           = c00[reg];
    mp[(size_t)(r0 + ro) * NCOL + c0 + 16 + l16]      = c01[reg];
    mp[(size_t)(r0 + 16 + ro) * NCOL + c0 + l16]      = c10[reg];
    mp[(size_t)(r0 + 16 + ro) * NCOL + c0 + 16 + l16] = c11[reg];
  }
}

// ---------------------------------------------------------------------------
// Kernel 3: reduce 8 K-split partials into Mp[0] (in place, per-thread safe).
// ---------------------------------------------------------------------------
__global__ __launch_bounds__(256) void md_reduce(float* __restrict__ Mp) {
  int idx = blockIdx.x * 256 + threadIdx.x;  // 65536 float4
  f32x4* M4 = (f32x4*)Mp;
  f32x4 s = M4[idx];
#pragma unroll
  for (int p = 1; p < 8; ++p) s += M4[p * 65536 + idx];
  M4[idx] = s;
}

// ---------------------------------------------------------------------------
// Kernel 4: out[i,f] = sum_j exp(-sum_k |M[i,f,k]-M[j,f,k]|) - 1
// grid 1024: f = b>>4, jt = b&15. Self term cancelled by acc=-1 in own tile.
// ---------------------------------------------------------------------------
__global__ __launch_bounds__(256) void md_pairwise(const float* __restrict__ M,
                                                   float* __restrict__ out) {
  __shared__ float ms[16 * KD];
  const int tid = threadIdx.x;
  const int f = blockIdx.x >> 4;
  const int jt = blockIdx.x & 15;
  const int j0 = jt * 16;

  if (tid < 64) {
    int j = tid >> 2, kc = tid & 3;
    *(float4*)&ms[j * KD + kc * 4] =
        *(const float4*)&M[(size_t)(j0 + j) * NCOL + f * KD + kc * 4];
  }

  float m[KD];
#pragma unroll
  for (int kc = 0; kc < 4; ++kc) {
    float4 v = *(const float4*)&M[(size_t)tid * NCOL + f * KD + kc * 4];
    m[kc * 4 + 0] = v.x;
    m[kc * 4 + 1] = v.y;
    m[kc * 4 + 2] = v.z;
    m[kc * 4 + 3] = v.w;
  }
  __syncthreads();

  float acc = ((tid >> 4) == jt) ? -1.0f : 0.0f;
#pragma unroll
  for (int j = 0; j < 16; ++j) {
    float l1 = 0.f;
#pragma unroll
    for (int k = 0; k < KD; ++k) l1 += fabsf(m[k] - ms[j * KD + k]);
    acc += __expf(-l1);
  }
  atomicAdd(&out[(size_t)tid * NFEAT + f], acc);
}

extern "C" void kernel_launch(void* const* d_in, const int* in_sizes, int n_in,
                              void* d_out, int out_size, void* d_ws, size_t ws_size,
                              hipStream_t stream) {
  const float* x = (const float*)d_in[0];
  const float* T = (const float*)d_in[1];
  float* out = (float*)d_out;

  char* ws = (char*)d_ws;                       // layout (13 MB total):
  ushort* Th = (ushort*)(ws);                   // [0, 2M)   T^t hi bf16
  ushort* Tl = (ushort*)(ws + (2u << 20));      // [2M, 4M)  T^t lo bf16
  ushort* xh = (ushort*)(ws + (4u << 20));      // [4M, 4.5M) x hi
  ushort* xl = (ushort*)(ws + (4u << 20) + (512u << 10));  // [4.5M, 5M) x lo
  float* Mp = (float*)(ws + (5u << 20));        // [5M, 13M) 8 K-split partials

  hipMemsetAsync(out, 0, (size_t)BATCH * NFEAT * sizeof(float), stream);
  md_prep<<<264, 256, 0, stream>>>(x, T, Th, Tl, xh, xl);
  md_mfma<<<512, 256, 0, stream>>>(xh, xl, Th, Tl, Mp);
  md_reduce<<<256, 256, 0, stream>>>(Mp);
  md_pairwise<<<1024, 256, 0, stream>>>(Mp, out);
}

// Round 4
// 42.115 us; speedup vs baseline: 1.7171x; 1.1806x over previous
//
#include <hip/hip_runtime.h>

#define BATCH 256
#define KDIM 1024
#define NFEAT 64
#define KD 16
#define NCOL (NFEAT * KD)  // 1024

typedef __attribute__((ext_vector_type(8))) short bf16x8;   // 8 bf16 (4 VGPR)
typedef __attribute__((ext_vector_type(4))) float f32x4;    // MFMA C/D
typedef __attribute__((ext_vector_type(4))) unsigned int u32x4;

__device__ __forceinline__ unsigned int bf16_hi(float f) {
  return __builtin_bit_cast(unsigned int, f) >> 16;  // truncation: residual goes to lo
}

// ---------------------------------------------------------------------------
// Kernel 1: prep. Blocks 0..255: transpose+convert T (1024x1024 f32, k-major)
// into Th/Tl [col][k] bf16 via a 64x64 LDS tile. Blocks 256..263: convert x
// row-major into xh/xl bf16 (k already contiguous).
// Split: xh = bf16_trunc(x), xl = bf16_trunc(x - xh)  (rel err ~2^-16).
// ---------------------------------------------------------------------------
__global__ __launch_bounds__(256) void md_prep(const float* __restrict__ x,
                                               const float* __restrict__ T,
                                               ushort* __restrict__ Th,
                                               ushort* __restrict__ Tl,
                                               ushort* __restrict__ xh,
                                               ushort* __restrict__ xl) {
  const int t = threadIdx.x;
  const int b = blockIdx.x;
  if (b < 256) {
    __shared__ float lds[64][65];  // +1 pad: transpose-read conflict-free
    const int k0 = (b >> 4) * 64, c0 = (b & 15) * 64;
    const float4* T4 = (const float4*)T;
#pragma unroll
    for (int rr = 0; rr < 4; ++rr) {
      int row = rr * 16 + (t >> 4);
      float4 v = T4[(size_t)(k0 + row) * 256 + (c0 >> 2) + (t & 15)];
      lds[row][(t & 15) * 4 + 0] = v.x;
      lds[row][(t & 15) * 4 + 1] = v.y;
      lds[row][(t & 15) * 4 + 2] = v.z;
      lds[row][(t & 15) * 4 + 3] = v.w;
    }
    __syncthreads();
    const int col = t >> 2, kc = (t & 3) * 16;
    unsigned int wh[8], wl[8];
#pragma unroll
    for (int kk = 0; kk < 16; ++kk) {
      float f = lds[kc + kk][col];
      unsigned int h = bf16_hi(f);
      float r = f - __builtin_bit_cast(float, h << 16);
      unsigned int lo = bf16_hi(r);
      if (kk & 1) { wh[kk >> 1] |= h << 16; wl[kk >> 1] |= lo << 16; }
      else        { wh[kk >> 1] = h;        wl[kk >> 1] = lo; }
    }
    size_t off = ((size_t)(c0 + col) * KDIM + k0 + kc) >> 1;  // u32 index
    u32x4* ph = (u32x4*)((unsigned int*)Th + off);
    u32x4* pl = (u32x4*)((unsigned int*)Tl + off);
    ph[0] = u32x4{wh[0], wh[1], wh[2], wh[3]};
    ph[1] = u32x4{wh[4], wh[5], wh[6], wh[7]};
    pl[0] = u32x4{wl[0], wl[1], wl[2], wl[3]};
    pl[1] = u32x4{wl[4], wl[5], wl[6], wl[7]};
  } else {
    const float4* x4 = (const float4*)x;
    uint2* xh2 = (uint2*)xh;
    uint2* xl2 = (uint2*)xl;
    int base = (b - 256) * 256 + t;
#pragma unroll
    for (int i = 0; i < 32; ++i) {
      int idx = base + i * 2048;  // 65536 float4 total
      float4 v = x4[idx];
      unsigned int h0 = bf16_hi(v.x), h1 = bf16_hi(v.y), h2 = bf16_hi(v.z), h3 = bf16_hi(v.w);
      float r0 = v.x - __builtin_bit_cast(float, h0 << 16);
      float r1 = v.y - __builtin_bit_cast(float, h1 << 16);
      float r2 = v.z - __builtin_bit_cast(float, h2 << 16);
      float r3 = v.w - __builtin_bit_cast(float, h3 << 16);
      xh2[idx] = make_uint2(h0 | (h1 << 16), h2 | (h3 << 16));
      xl2[idx] = make_uint2(bf16_hi(r0) | (bf16_hi(r1) << 16),
                            bf16_hi(r2) | (bf16_hi(r3) << 16));
    }
  }
}

// ---------------------------------------------------------------------------
// Kernel 2: MFMA GEMM. M = xh*Th + xh*Tl + xl*Th (3-product split-bf16).
// Wave = 32x32 out tile, K=128 slice. 2048 waves (512 blocks). Frags read
// straight from global (16B contiguous in k, both operands — Tt is
// pre-transposed). Partials to Mp[ks] (no atomics).
// ---------------------------------------------------------------------------
__global__ __launch_bounds__(256, 2) void md_mfma(const ushort* __restrict__ xh,
                                                  const ushort* __restrict__ xl,
                                                  const ushort* __restrict__ Th,
                                                  const ushort* __restrict__ Tl,
                                                  float* __restrict__ Mp) {
  const int tid = threadIdx.x;
  const int l = tid & 63;
  const int W = blockIdx.x * 4 + (tid >> 6);
  const int tc = W & 31, tr = (W >> 5) & 7, ks = W >> 8;
  const int r0 = tr * 32, c0 = tc * 32, k0 = ks * 128;
  const int l16 = l & 15, g = l >> 4;

  const ushort* pah = xh + (size_t)(r0 + l16) * KDIM + k0 + 8 * g;
  const ushort* pal = xl + (size_t)(r0 + l16) * KDIM + k0 + 8 * g;
  const ushort* pbh = Th + (size_t)(c0 + l16) * KDIM + k0 + 8 * g;
  const ushort* pbl = Tl + (size_t)(c0 + l16) * KDIM + k0 + 8 * g;

  f32x4 c00 = {0.f, 0.f, 0.f, 0.f}, c01 = c00, c10 = c00, c11 = c00;

#pragma unroll
  for (int s = 0; s < 4; ++s) {
    const int o = s * 32;
    bf16x8 ah0 = *(const bf16x8*)(pah + o);
    bf16x8 ah1 = *(const bf16x8*)(pah + o + 16 * KDIM);
    bf16x8 al0 = *(const bf16x8*)(pal + o);
    bf16x8 al1 = *(const bf16x8*)(pal + o + 16 * KDIM);
    bf16x8 bh0 = *(const bf16x8*)(pbh + o);
    bf16x8 bh1 = *(const bf16x8*)(pbh + o + 16 * KDIM);
    bf16x8 bl0 = *(const bf16x8*)(pbl + o);
    bf16x8 bl1 = *(const bf16x8*)(pbl + o + 16 * KDIM);

    c00 = __builtin_amdgcn_mfma_f32_16x16x32_bf16(ah0, bh0, c00, 0, 0, 0);
    c01 = __builtin_amdgcn_mfma_f32_16x16x32_bf16(ah0, bh1, c01, 0, 0, 0);
    c10 = __builtin_amdgcn_mfma_f32_16x16x32_bf16(ah1, bh0, c10, 0, 0, 0);
    c11 = __builtin_amdgcn_mfma_f32_16x16x32_bf16(ah1, bh1, c11, 0, 0, 0);
    c00 = __builtin_amdgcn_mfma_f32_16x16x32_bf16(ah0, bl0, c00, 0, 0, 0);
    c01 = __builtin_amdgcn_mfma_f32_16x16x32_bf16(ah0, bl1, c01, 0, 0, 0);
    c10 = __builtin_amdgcn_mfma_f32_16x16x32_bf16(ah1, bl0, c10, 0, 0, 0);
    c11 = __builtin_amdgcn_mfma_f32_16x16x32_bf16(ah1, bl1, c11, 0, 0, 0);
    c00 = __builtin_amdgcn_mfma_f32_16x16x32_bf16(al0, bh0, c00, 0, 0, 0);
    c01 = __builtin_amdgcn_mfma_f32_16x16x32_bf16(al0, bh1, c01, 0, 0, 0);
    c10 = __builtin_amdgcn_mfma_f32_16x16x32_bf16(al1, bh0, c10, 0, 0, 0);
    c11 = __builtin_amdgcn_mfma_f32_16x16x32_bf16(al1, bh1, c11, 0, 0, 0);
  }

  float* mp = Mp + (size_t)ks * (BATCH * NCOL);
#pragma unroll
  for (int reg = 0; reg < 4; ++reg) {
    int ro = g * 4 + reg;  // C/D: col = lane&15, row = (lane>>4)*4 + reg
    mp[(size_t)(r0 + ro) * NCOL + c0 + l16]           = c00[reg];
    mp[(size_t)(r0 + ro) * NCOL + c0 + 16 + l16]      = c01[reg];
    mp[(size_t)(r0 + 16 + ro) * NCOL + c0 + l16]      = c10[reg];
    mp[(size_t)(r0 + 16 + ro) * NCOL + c0 + 16 + l16] = c11[reg];
  }
}

// ---------------------------------------------------------------------------
// Kernel 3: reduce 8 K-split partials into Mp[0] (in place, per-thread safe).
// ---------------------------------------------------------------------------
__global__ __launch_bounds__(256) void md_reduce(float* __restrict__ Mp) {
  int idx = blockIdx.x * 256 + threadIdx.x;  // 65536 float4
  f32x4* M4 = (f32x4*)Mp;
  f32x4 s = M4[idx];
#pragma unroll
  for (int p = 1; p < 8; ++p) s += M4[p * 65536 + idx];
  M4[idx] = s;
}

// ---------------------------------------------------------------------------
// Kernel 4: out[i,f] = sum_j exp(-sum_k |M[i,f,k]-M[j,f,k]|) - 1
// ATOMIC-FREE: grid 256 = (f << 2) | ig.  256 threads: lane = i within
// 64-row group, wave wv owns j-range [wv*64, wv*64+64).  All M[:,f,:] staged
// in LDS (16 KB, broadcast reads).  Cross-wave reduce in LDS, plain stores,
// self term exp(0)=1 removed by the final -1.
// ---------------------------------------------------------------------------
__global__ __launch_bounds__(256) void md_pairwise(const float* __restrict__ M,
                                                   float* __restrict__ out) {
  __shared__ float ms[BATCH * KD];   // 16 KB: all j rows for this f
  __shared__ float part[256];        // cross-wave partials
  const int tid = threadIdx.x;
  const int f = blockIdx.x >> 2;
  const int ig = blockIdx.x & 3;
  const int lane = tid & 63;
  const int wv = tid >> 6;
  const int i = ig * 64 + lane;

  // stage: 4 iters x (64 j-rows, 4 float4 chunks per row)
#pragma unroll
  for (int it = 0; it < 4; ++it) {
    int j = it * 64 + (tid >> 2);
    int kc = tid & 3;
    *(float4*)&ms[j * KD + kc * 4] =
        *(const float4*)&M[(size_t)j * NCOL + f * KD + kc * 4];
  }

  float m[KD];
#pragma unroll
  for (int kc = 0; kc < 4; ++kc) {
    float4 v = *(const float4*)&M[(size_t)i * NCOL + f * KD + kc * 4];
    m[kc * 4 + 0] = v.x;
    m[kc * 4 + 1] = v.y;
    m[kc * 4 + 2] = v.z;
    m[kc * 4 + 3] = v.w;
  }
  __syncthreads();

  float acc = 0.f;
  const int j0 = wv * 64;
#pragma unroll 4
  for (int j = 0; j < 64; ++j) {
    float l1 = 0.f;
#pragma unroll
    for (int k = 0; k < KD; ++k) l1 += fabsf(m[k] - ms[(j0 + j) * KD + k]);
    acc += __expf(-l1);
  }
  part[tid] = acc;
  __syncthreads();

  if (tid < 64) {
    float s = part[tid] + part[tid + 64] + part[tid + 128] + part[tid + 192];
    out[(size_t)(ig * 64 + tid) * NFEAT + f] = s - 1.0f;  // remove self term
  }
}

extern "C" void kernel_launch(void* const* d_in, const int* in_sizes, int n_in,
                              void* d_out, int out_size, void* d_ws, size_t ws_size,
                              hipStream_t stream) {
  const float* x = (const float*)d_in[0];
  const float* T = (const float*)d_in[1];
  float* out = (float*)d_out;

  char* ws = (char*)d_ws;                       // layout (13 MB total):
  ushort* Th = (ushort*)(ws);                   // [0, 2M)   T^t hi bf16
  ushort* Tl = (ushort*)(ws + (2u << 20));      // [2M, 4M)  T^t lo bf16
  ushort* xh = (ushort*)(ws + (4u << 20));      // [4M, 4.5M) x hi
  ushort* xl = (ushort*)(ws + (4u << 20) + (512u << 10));  // [4.5M, 5M) x lo
  float* Mp = (float*)(ws + (5u << 20));        // [5M, 13M) 8 K-split partials

  md_prep<<<264, 256, 0, stream>>>(x, T, Th, Tl, xh, xl);
  md_mfma<<<512, 256, 0, stream>>>(xh, xl, Th, Tl, Mp);
  md_reduce<<<256, 256, 0, stream>>>(Mp);
  md_pairwise<<<256, 256, 0, stream>>>(Mp, out);
}